// Round 2
// baseline (304.590 us; speedup 1.0000x reference)
//
#include <hip/hip_runtime.h>

// Problem constants
#define B_    64
#define C_    3
#define H_    384
#define W_    384
#define P_    16
#define E_    768
#define N_    576                 // patches per image
#define M_    (B_ * N_)           // 36864 total patches
#define K_    (C_ * P_ * P_)      // 768 reduction dim
#define HW_   (H_ * W_)
#define CHW_  (C_ * H_ * W_)

// GEMM tiling
#define BM    128
#define BN    128
#define BK    64
#define KITERS (K_ / BK)          // 12

typedef __attribute__((ext_vector_type(8))) short  short8;   // bf16x8 MFMA operand
typedef __attribute__((ext_vector_type(4))) float  f32x4;    // MFMA accumulator

// round-to-nearest-even f32 pair -> packed bf16x2 (low = a). Bitwise identical
// to the original gather's f2bf, so outputs match the prior passing kernel.
__device__ __forceinline__ unsigned int rnepair(float a, float b) {
    unsigned ua = __float_as_uint(a), ub = __float_as_uint(b);
    ua += 0x7FFFu + ((ua >> 16) & 1u);
    ub += 0x7FFFu + ((ub >> 16) & 1u);
    return (ua >> 16) | (ub & 0xFFFF0000u);
}

// 16B load with only 4B alignment guaranteed (xs is arbitrary). memcpy lets
// the compiler pick the widest legal load; correct for any alignment.
__device__ __forceinline__ float4 ld16u(const float* p) {
    float4 v;
    __builtin_memcpy(&v, p, 16);
    return v;
}

// async global->LDS, 16B per lane (global_load_lds_dwordx4)
__device__ __forceinline__ void gload_lds16(const void* g, void* l) {
    __builtin_amdgcn_global_load_lds(
        (const __attribute__((address_space(1))) unsigned int*)g,
        (__attribute__((address_space(3))) unsigned int*)l,
        16, 0, 0);
}

// Phase 1: w [E][K] fp32 -> bf16 (B^T layout already)
__global__ __launch_bounds__(256)
void wconv_kernel(const float* __restrict__ w, unsigned short* __restrict__ Wb)
{
    const unsigned g = blockIdx.x * 256 + threadIdx.x;   // < E_*K_/4
    float4 f = ((const float4*)w)[g];
    uint2 pk;
    pk.x = rnepair(f.x, f.y);
    pk.y = rnepair(f.z, f.w);
    *(uint2*)(Wb + (size_t)g * 4) = pk;
}

// ---------------------------------------------------------------------------
// Fused gather+GEMM. A is gathered per K-tile straight from x (fp32) into
// registers, converted to bf16, and written XOR-swizzled into LDS. Removes
// the 113 MB fp32 gather read + 57 MB bf16 A write + 57 MB A re-read round
// trip and one kernel launch vs the unfused baseline.
//
// LDS A layout: row p (patch) = 128B; byte offset within row XORed with
// ((p&7)<<4) on BOTH write and read (write side would otherwise be a 32-way
// bank conflict: 64 lanes x 16B land on 2 slot columns; read side 16-way).
// ---------------------------------------------------------------------------
__global__ __launch_bounds__(256)
void fused_gemm(const float* __restrict__ x,
                const int*   __restrict__ ys,
                const int*   __restrict__ xs,
                const unsigned short* __restrict__ Wb,
                const float* __restrict__ bias,
                float*       __restrict__ out)
{
    __shared__ __align__(16) unsigned short Asm[BM * BK];   // 16 KB
    __shared__ __align__(16) unsigned short Bsm[BN * BK];   // 16 KB

    const int t    = threadIdx.x;
    const int wave = t >> 6;
    const int lane = t & 63;

    // XCD-aware swizzle: 1728 blocks = 8 xcd-groups x 36 m-tiles x 6 e-tiles.
    // 6 e-tiles sharing an A-slab (same x region) land on one XCD's L2.
    const int b   = blockIdx.x;
    const int xcd = b & 7;
    const int idx = b >> 3;              // 0..215
    const int mt  = xcd * 36 + idx / 6;  // m-tile 0..287
    const int et  = idx % 6;
    const int m0  = mt * BM;
    const int e0  = et * BN;

    // ---- A gather role: thread -> (patch p = t>>1, half h = t&1) ----
    // Per K-tile (BK=64 = 4 patch-rows of 16 cols, single channel):
    // half h covers rows py0+2h, py0+2h+1 (32 elems = 8x ld16u).
    const int p  = t >> 1;
    const int h  = t & 1;
    const int gp = m0 + p;
    const int bimg  = gp / N_;
    const int pbase = bimg * CHW_ + ys[gp] * W_ + xs[gp];
    const float* xrow = x + pbase + 2 * h * W_;   // + c*HW_ + py0*W_ per iter

    char* aw = (char*)Asm + p * 128;     // swizzled A write base
    const int awz = (p & 7) << 4;
    const int h64 = h * 64;

    // ---- B staging role (global_load_lds), unchanged from proven kernel ----
    const int r8 = lane >> 3;            // 0..7
    const int c8 = (lane & 7) * 8;       // bf16 elem col (0..56 step 8)
    const unsigned short* Bg = Wb + (size_t)(e0 + wave * 32 + r8) * K_ + c8;
    unsigned short* Bl = &Bsm[(wave * 32 + r8) * BK + c8];

    // ---- compute role ----
    const int wr   = (wave >> 1) * 64;
    const int wc   = (wave & 1) * 64;
    const int lm   = lane & 15;
    const int quad = lane >> 4;
    const char* Ard = (const char*)Asm + (wr + lm) * 128;
    const int rswz = (lm & 7) << 4;      // == (row&7)<<4 since wr+16i ≡ 0 mod 8

    f32x4 acc[4][4];
#pragma unroll
    for (int i = 0; i < 4; ++i)
#pragma unroll
        for (int j = 0; j < 4; ++j)
            acc[i][j] = (f32x4){0.f, 0.f, 0.f, 0.f};

    // prologue: gather A regs for K-tile 0 (c=0, py0=0)
    float4 fr[8];
#pragma unroll
    for (int m = 0; m < 4; ++m) fr[m]     = ld16u(xrow + 4 * m);
#pragma unroll
    for (int m = 0; m < 4; ++m) fr[4 + m] = ld16u(xrow + W_ + 4 * m);

#pragma unroll 1
    for (int it = 0; it < KITERS; ++it) {
        // issue async B stage for this K-tile
        const unsigned short* bg = Bg + it * BK;
#pragma unroll
        for (int inst = 0; inst < 4; ++inst)
            gload_lds16(bg + (size_t)(inst * 8) * K_, Bl + inst * 8 * BK);

        // convert + swizzled ds_write_b128 of this tile's A regs
#pragma unroll
        for (int j = 0; j < 4; ++j) {
            uint4 wv;
            wv.x = rnepair(fr[2*j].x,   fr[2*j].y);
            wv.y = rnepair(fr[2*j].z,   fr[2*j].w);
            wv.z = rnepair(fr[2*j+1].x, fr[2*j+1].y);
            wv.w = rnepair(fr[2*j+1].z, fr[2*j+1].w);
            *(uint4*)(aw + ((h64 + j * 16) ^ awz)) = wv;
        }

        __syncthreads();   // B landed (vmcnt drain), A written -> tile ready

        // prefetch next tile's A into regs; latency hides under MFMA below
        if (it + 1 < KITERS) {
            const int itn = it + 1;
            const float* rp = xrow + (itn >> 2) * HW_ + ((itn & 3) << 2) * W_;
#pragma unroll
            for (int m = 0; m < 4; ++m) fr[m]     = ld16u(rp + 4 * m);
#pragma unroll
            for (int m = 0; m < 4; ++m) fr[4 + m] = ld16u(rp + W_ + 4 * m);
        }

#pragma unroll
        for (int s = 0; s < 2; ++s) {            // two K=32 sub-steps
            short8 af[4], bfr[4];
#pragma unroll
            for (int i = 0; i < 4; ++i)
                af[i] = *(const short8*)(Ard + i * (16 * 128)
                                             + ((s * 64 + quad * 16) ^ rswz));
#pragma unroll
            for (int j = 0; j < 4; ++j)
                bfr[j] = *(const short8*)&Bsm[(wc + j * 16 + lm) * BK + s * 32 + quad * 8];
#pragma unroll
            for (int i = 0; i < 4; ++i)
#pragma unroll
                for (int j = 0; j < 4; ++j)
                    acc[i][j] = __builtin_amdgcn_mfma_f32_16x16x32_bf16(af[i], bfr[j], acc[i][j], 0, 0, 0);
        }

        __syncthreads();   // protect LDS before next tile's writes
    }

    // epilogue: C/D layout col=lane&15, row=quad*4+reg (m89-verified)
    float bv[4];
#pragma unroll
    for (int j = 0; j < 4; ++j) bv[j] = bias[e0 + wc + j * 16 + lm];

#pragma unroll
    for (int i = 0; i < 4; ++i) {
#pragma unroll
        for (int j = 0; j < 4; ++j) {
            const int eo = e0 + wc + j * 16 + lm;
#pragma unroll
            for (int r = 0; r < 4; ++r) {
                const int mo = m0 + wr + i * 16 + quad * 4 + r;
                out[(size_t)mo * E_ + eo] = acc[i][j][r] + bv[j];
            }
        }
    }
}

__global__ void pos_kernel(const int* __restrict__ ys, const int* __restrict__ xs,
                           float* __restrict__ outp)
{
    int i = blockIdx.x * blockDim.x + threadIdx.x;
    if (i < M_) {
        outp[2 * i]     = (float)ys[i];
        outp[2 * i + 1] = (float)xs[i];
    }
}

extern "C" void kernel_launch(void* const* d_in, const int* in_sizes, int n_in,
                              void* d_out, int out_size, void* d_ws, size_t ws_size,
                              hipStream_t stream)
{
    const float* x    = (const float*)d_in[0];
    const int*   ys   = (const int*)d_in[1];
    const int*   xs   = (const int*)d_in[2];
    const float* w    = (const float*)d_in[3];
    const float* bias = (const float*)d_in[4];
    float* out = (float*)d_out;

    // workspace: W_bf16 [E][768] only (A round trip eliminated)
    unsigned short* Wb = (unsigned short*)d_ws;

    wconv_kernel<<<(E_ * K_ / 4) / 256, 256, 0, stream>>>(w, Wb);

    fused_gemm<<<(M_ / BM) * (E_ / BN), 256, 0, stream>>>(x, ys, xs, Wb, bias, out);

    float* outp = out + (size_t)M_ * E_;
    pos_kernel<<<(M_ + 255) / 256, 256, 0, stream>>>(ys, xs, outp);
}